// Round 4
// baseline (388.717 us; speedup 1.0000x reference)
//
#include <hip/hip_runtime.h>
#include <hip/hip_cooperative_groups.h>

namespace cg = cooperative_groups;

#define H    256
#define H2   512
#define ROWS 16
#define LN_EPS 1e-5f

#define SORT_NB  1024
#define SORT_TPB 256

typedef _Float16 half4v __attribute__((ext_vector_type(4)));
typedef float    f32x4  __attribute__((ext_vector_type(4)));

// ---------------- prep: zero counts + build fragment-ordered f16 weights ----------------
// WpA layout: quad q = ((kb16*16 + nb)*64 + lane); element j of quad = Wp[k][n]
// with k = kb16*16 + 4*(lane>>4) + j, n = nb*16 + (lane&15).  (A-fragment order for
// v_mfma_f32_16x16x16_f16 with A = W^T tile; mapping verified by round-3 pass.)

__global__ __launch_bounds__(256) void k_prep(const float* __restrict__ Wp,
        const float* __restrict__ Wf, _Float16* __restrict__ WpA,
        _Float16* __restrict__ WfsA, int* __restrict__ counts, int G) {
    const int tid = blockIdx.x * 256 + threadIdx.x;
    const int stride = gridDim.x * 256;
    for (int i = tid; i < G; i += stride) counts[i] = 0;
    for (int q = tid; q < 32 * 16 * 64; q += stride) {          // GEMM1: K=512 -> 32 kb16
        const int l  = q & 63;
        const int nb = (q >> 6) & 15;
        const int kb = q >> 10;
        const int n  = nb * 16 + (l & 15);
        const int k  = kb * 16 + 4 * (l >> 4);
        half4v v;
        v[0] = (_Float16)Wp[(size_t)(k + 0) * H + n];
        v[1] = (_Float16)Wp[(size_t)(k + 1) * H + n];
        v[2] = (_Float16)Wp[(size_t)(k + 2) * H + n];
        v[3] = (_Float16)Wp[(size_t)(k + 3) * H + n];
        *(half4v*)&WpA[(size_t)q * 4] = v;
    }
    for (int q = tid; q < 16 * 16 * 64; q += stride) {          // GEMM2: K=256, Wf folded 3->1
        const int l  = q & 63;
        const int nb = (q >> 6) & 15;
        const int kb = q >> 10;
        const int n  = nb * 16 + (l & 15);
        const int k  = kb * 16 + 4 * (l >> 4);
        half4v v;
        #pragma unroll
        for (int j = 0; j < 4; ++j) {
            const int kj = k + j;
            v[j] = (_Float16)(Wf[(size_t)kj * H + n] + Wf[(size_t)(kj + H) * H + n]
                              + Wf[(size_t)(kj + 2 * H) * H + n]);
        }
        *(half4v*)&WfsA[(size_t)q * 4] = v;
    }
}

// ---------------- cooperative sort: hist(rank in regs) -> scan -> scatter ----------------

__global__ __launch_bounds__(SORT_TPB) void k_sort(const int* __restrict__ fid,
        int* __restrict__ counts, int* __restrict__ offsets,
        int* __restrict__ idx_sorted, int N, int G) {
    cg::grid_group grid = cg::this_grid();
    const int tid = blockIdx.x * SORT_TPB + threadIdx.x;
    const int total = SORT_NB * SORT_TPB;
    // N <= 2*total (500000 <= 524288)
    int f0 = -1, f1 = -1, r0 = 0, r1 = 0;
    if (tid < N)          { f0 = fid[tid];          r0 = atomicAdd(&counts[f0], 1); }
    if (tid + total < N)  { f1 = fid[tid + total];  r1 = atomicAdd(&counts[f1], 1); }
    grid.sync();
    if (blockIdx.x == 0) {                          // 256-thread shuffle scan of G counters
        __shared__ int wsum[4];
        const int tt = threadIdx.x;
        const int lane = tt & 63, ww = tt >> 6;
        const int base = tt * 32;
        int pre[32];
        int s = 0;
        if (base + 32 <= G) {
            #pragma unroll
            for (int j = 0; j < 32; j += 4) {
                int4 c = *(const int4*)&counts[base + j];
                pre[j]     = s; s += c.x;
                pre[j + 1] = s; s += c.y;
                pre[j + 2] = s; s += c.z;
                pre[j + 3] = s; s += c.w;
            }
        } else {
            #pragma unroll
            for (int j = 0; j < 32; ++j) {
                int c = (base + j < G) ? counts[base + j] : 0;
                pre[j] = s; s += c;
            }
        }
        int inc = s;
        #pragma unroll
        for (int off = 1; off < 64; off <<= 1) {
            int u = __shfl_up(inc, off, 64);
            if (lane >= off) inc += u;
        }
        if (lane == 63) wsum[ww] = inc;
        __syncthreads();
        int wb = 0;
        #pragma unroll
        for (int i = 0; i < 4; ++i) wb += (i < ww) ? wsum[i] : 0;
        const int tb = wb + inc - s;                // exclusive base for this thread
        if (base + 32 <= G) {
            #pragma unroll
            for (int j = 0; j < 32; j += 4) {
                int4 o = make_int4(tb + pre[j], tb + pre[j + 1], tb + pre[j + 2], tb + pre[j + 3]);
                *(int4*)&offsets[base + j] = o;
            }
        } else {
            for (int j = 0; j < 32; ++j)
                if (base + j < G) offsets[base + j] = tb + pre[j];
        }
    }
    grid.sync();
    if (tid < N)         idx_sorted[offsets[f0] + r0] = tid;
    if (tid + total < N) idx_sorted[offsets[f1] + r1] = tid + total;
}

// ---------------- segment mean+max gather (1 wave/group, idx prefetch, f16 out) ----------------

__global__ __launch_bounds__(256) void k_reduce(const float* __restrict__ x,
        const int* __restrict__ idx, const int* __restrict__ offsets,
        const int* __restrict__ counts, _Float16* __restrict__ pooledH, int G) {
    int g = __builtin_amdgcn_readfirstlane(blockIdx.x * 4 + (threadIdx.x >> 6));
    if (g >= G) return;
    const int t = threadIdx.x & 63;
    const int start = offsets[g];
    const int cnt   = counts[g];
    const float4* __restrict__ xv = (const float4*)x;

    float4 s = make_float4(0.f, 0.f, 0.f, 0.f);
    const float ninf = -__builtin_inff();
    float4 m = make_float4(ninf, ninf, ninf, ninf);

    int j = 0;
    if (cnt >= 4) {
        int p0 = idx[start + 0], p1 = idx[start + 1];
        int p2 = idx[start + 2], p3 = idx[start + 3];
        for (; j + 8 <= cnt; j += 4) {
            const int c0 = p0, c1 = p1, c2 = p2, c3 = p3;
            p0 = idx[start + j + 4]; p1 = idx[start + j + 5];
            p2 = idx[start + j + 6]; p3 = idx[start + j + 7];
            float4 a = xv[(size_t)c0 * 64 + t];
            float4 b = xv[(size_t)c1 * 64 + t];
            float4 c = xv[(size_t)c2 * 64 + t];
            float4 d = xv[(size_t)c3 * 64 + t];
            s.x += (a.x + b.x) + (c.x + d.x);
            s.y += (a.y + b.y) + (c.y + d.y);
            s.z += (a.z + b.z) + (c.z + d.z);
            s.w += (a.w + b.w) + (c.w + d.w);
            m.x = fmaxf(m.x, fmaxf(fmaxf(a.x, b.x), fmaxf(c.x, d.x)));
            m.y = fmaxf(m.y, fmaxf(fmaxf(a.y, b.y), fmaxf(c.y, d.y)));
            m.z = fmaxf(m.z, fmaxf(fmaxf(a.z, b.z), fmaxf(c.z, d.z)));
            m.w = fmaxf(m.w, fmaxf(fmaxf(a.w, b.w), fmaxf(c.w, d.w)));
        }
        {   // consume last prefetched quartet
            float4 a = xv[(size_t)p0 * 64 + t];
            float4 b = xv[(size_t)p1 * 64 + t];
            float4 c = xv[(size_t)p2 * 64 + t];
            float4 d = xv[(size_t)p3 * 64 + t];
            s.x += (a.x + b.x) + (c.x + d.x);
            s.y += (a.y + b.y) + (c.y + d.y);
            s.z += (a.z + b.z) + (c.z + d.z);
            s.w += (a.w + b.w) + (c.w + d.w);
            m.x = fmaxf(m.x, fmaxf(fmaxf(a.x, b.x), fmaxf(c.x, d.x)));
            m.y = fmaxf(m.y, fmaxf(fmaxf(a.y, b.y), fmaxf(c.y, d.y)));
            m.z = fmaxf(m.z, fmaxf(fmaxf(a.z, b.z), fmaxf(c.z, d.z)));
            m.w = fmaxf(m.w, fmaxf(fmaxf(a.w, b.w), fmaxf(c.w, d.w)));
            j += 4;
        }
    }
    for (; j < cnt; ++j) {
        int i0 = idx[start + j];
        float4 a = xv[(size_t)i0 * 64 + t];
        s.x += a.x; s.y += a.y; s.z += a.z; s.w += a.w;
        m.x = fmaxf(m.x, a.x); m.y = fmaxf(m.y, a.y);
        m.z = fmaxf(m.z, a.z); m.w = fmaxf(m.w, a.w);
    }
    const float inv = 1.0f / (float)((cnt > 1) ? cnt : 1);
    half4v mh, xh;
    mh[0] = (_Float16)(s.x * inv); mh[1] = (_Float16)(s.y * inv);
    mh[2] = (_Float16)(s.z * inv); mh[3] = (_Float16)(s.w * inv);
    xh[0] = (_Float16)m.x; xh[1] = (_Float16)m.y;
    xh[2] = (_Float16)m.z; xh[3] = (_Float16)m.w;
    *(half4v*)&pooledH[(size_t)g * H2 + 4 * t]     = mh;   // mean -> cols [0,256)
    *(half4v*)&pooledH[(size_t)g * H2 + H + 4 * t] = xh;   // max  -> cols [256,512)
}

// ---------------- fused MLP, MFMA f16, fragment-ordered LDS (all b64 linear) ----------------
// D^T = W^T(A) x pooled^T(B). Lane l, reg r of fragment (nb): row m = l&15,
// col n = nb*16 + 4*(l>>4) + r. LN1 output writes land exactly on GEMM2 B slots.

__global__ __launch_bounds__(256) void k_mlp(const _Float16* __restrict__ pooledH,
        const _Float16* __restrict__ WpA, const float* __restrict__ bp,
        const float* __restrict__ g1, const float* __restrict__ b1,
        const _Float16* __restrict__ WfsA, const float* __restrict__ bf,
        const float* __restrict__ g2, const float* __restrict__ b2,
        float* __restrict__ out, int G) {
    __shared__ _Float16 spB[32 * 64 * 4];   // 16 KB: pooled B-fragments (32 kb16)
    __shared__ _Float16 sA[4 * 16 * 64 * 4];// 32 KB: weight A-fragment tile (4 kb16 x 16 nb)
    __shared__ _Float16 sfB[16 * 64 * 4];   //  8 KB: func B-fragments (16 kb16)
    __shared__ float red[4][16][2];

    const int t   = threadIdx.x;
    const int l   = t & 63;
    const int w   = t >> 6;
    const int li  = l & 15;
    const int grp = l >> 4;
    const int g0  = blockIdx.x * ROWS;

    // stage pooled rows into fragment-ordered spB (b64 linear LDS writes)
    #pragma unroll
    for (int jj = 0; jj < 8; ++jj) {
        const int q = t + jj * 256;
        const int kb16 = q >> 6, ll = q & 63;
        *(half4v*)&spB[q * 4] =
            *(const half4v*)&pooledH[(size_t)(g0 + (ll & 15)) * H2 + kb16 * 16 + 4 * (ll >> 4)];
    }

    f32x4 acc[4];
    #pragma unroll
    for (int f = 0; f < 4; ++f) acc[f] = (f32x4)(0.f);

    // ---- GEMM1: K = 512, tiles of 64
    for (int k0 = 0; k0 < H2; k0 += 64) {
        {
            const int4* src = (const int4*)WpA + (size_t)(k0 >> 4) * 512;
            int4* dst = (int4*)sA;
            #pragma unroll
            for (int jj = 0; jj < 8; ++jj) dst[t + jj * 256] = src[t + jj * 256];
        }
        __syncthreads();
        #pragma unroll
        for (int kb = 0; kb < 4; ++kb) {
            half4v bfrag = *(const half4v*)&spB[(((k0 >> 4) + kb) * 64 + l) * 4];
            #pragma unroll
            for (int f = 0; f < 4; ++f) {
                const int nb = 4 * w + f;
                half4v afrag = *(const half4v*)&sA[((kb * 16 + nb) * 64 + l) * 4];
                acc[f] = __builtin_amdgcn_mfma_f32_16x16x16f16(afrag, bfrag, acc[f], 0, 0, 0);
            }
        }
        __syncthreads();
    }

    // ---- bias + LN1 + ReLU -> sfB (writes are this lane's own GEMM2 B slots)
    {
        f32x4 vv[4], g1v[4], b1v[4];
        float sum = 0.f, sq = 0.f;
        #pragma unroll
        for (int f = 0; f < 4; ++f) {
            const int n0 = 64 * w + 16 * f + 4 * grp;
            f32x4 bb = *(const f32x4*)&bp[n0];
            g1v[f] = *(const f32x4*)&g1[n0];
            b1v[f] = *(const f32x4*)&b1[n0];
            #pragma unroll
            for (int r = 0; r < 4; ++r) {
                float v = acc[f][r] + bb[r];
                vv[f][r] = v;
                sum += v; sq += v * v;
            }
        }
        sum += __shfl_xor(sum, 16, 64); sq += __shfl_xor(sq, 16, 64);
        sum += __shfl_xor(sum, 32, 64); sq += __shfl_xor(sq, 32, 64);
        if (grp == 0) { red[w][li][0] = sum; red[w][li][1] = sq; }
        __syncthreads();
        const float S = red[0][li][0] + red[1][li][0] + red[2][li][0] + red[3][li][0];
        const float Q = red[0][li][1] + red[1][li][1] + red[2][li][1] + red[3][li][1];
        const float mu  = S * (1.0f / H);
        const float var = Q * (1.0f / H) - mu * mu;
        const float rs  = rsqrtf(var + LN_EPS);
        #pragma unroll
        for (int f = 0; f < 4; ++f) {
            half4v hv;
            #pragma unroll
            for (int r = 0; r < 4; ++r)
                hv[r] = (_Float16)fmaxf((vv[f][r] - mu) * rs * g1v[f][r] + b1v[f][r], 0.f);
            *(half4v*)&sfB[((4 * w + f) * 64 + l) * 4] = hv;
        }
    }

    // ---- GEMM2: K = 256, tiles of 64
    f32x4 acc2[4];
    #pragma unroll
    for (int f = 0; f < 4; ++f) acc2[f] = (f32x4)(0.f);

    for (int k0 = 0; k0 < H; k0 += 64) {
        {
            const int4* src = (const int4*)WfsA + (size_t)(k0 >> 4) * 512;
            int4* dst = (int4*)sA;
            #pragma unroll
            for (int jj = 0; jj < 8; ++jj) dst[t + jj * 256] = src[t + jj * 256];
        }
        __syncthreads();
        #pragma unroll
        for (int kb = 0; kb < 4; ++kb) {
            half4v bfrag = *(const half4v*)&sfB[(((k0 >> 4) + kb) * 64 + l) * 4];
            #pragma unroll
            for (int f = 0; f < 4; ++f) {
                const int nb = 4 * w + f;
                half4v afrag = *(const half4v*)&sA[((kb * 16 + nb) * 64 + l) * 4];
                acc2[f] = __builtin_amdgcn_mfma_f32_16x16x16f16(afrag, bfrag, acc2[f], 0, 0, 0);
            }
        }
        __syncthreads();
    }

    // ---- bias + LN2 + ReLU -> out
    {
        f32x4 vv[4], g2v[4], b2v[4];
        float sum = 0.f, sq = 0.f;
        #pragma unroll
        for (int f = 0; f < 4; ++f) {
            const int n0 = 64 * w + 16 * f + 4 * grp;
            f32x4 bb = *(const f32x4*)&bf[n0];
            g2v[f] = *(const f32x4*)&g2[n0];
            b2v[f] = *(const f32x4*)&b2[n0];
            #pragma unroll
            for (int r = 0; r < 4; ++r) {
                float v = acc2[f][r] + bb[r];
                vv[f][r] = v;
                sum += v; sq += v * v;
            }
        }
        sum += __shfl_xor(sum, 16, 64); sq += __shfl_xor(sq, 16, 64);
        sum += __shfl_xor(sum, 32, 64); sq += __shfl_xor(sq, 32, 64);
        if (grp == 0) { red[w][li][0] = sum; red[w][li][1] = sq; }
        __syncthreads();
        const float S = red[0][li][0] + red[1][li][0] + red[2][li][0] + red[3][li][0];
        const float Q = red[0][li][1] + red[1][li][1] + red[2][li][1] + red[3][li][1];
        const float mu  = S * (1.0f / H);
        const float var = Q * (1.0f / H) - mu * mu;
        const float rs  = rsqrtf(var + LN_EPS);
        const int grow = g0 + li;
        #pragma unroll
        for (int f = 0; f < 4; ++f) {
            const int n0 = 64 * w + 16 * f + 4 * grp;
            f32x4 o;
            #pragma unroll
            for (int r = 0; r < 4; ++r)
                o[r] = fmaxf((vv[f][r] - mu) * rs * g2v[f][r] + b2v[f][r], 0.f);
            if (grow < G) *(f32x4*)&out[(size_t)grow * H + n0] = o;
        }
    }
}

// ---------------- launch ----------------

extern "C" void kernel_launch(void* const* d_in, const int* in_sizes, int n_in,
                              void* d_out, int out_size, void* d_ws, size_t ws_size,
                              hipStream_t stream) {
    const float* x   = (const float*)d_in[0];
    const int*   fid = (const int*)d_in[2];
    const float* Wp  = (const float*)d_in[3];
    const float* bp  = (const float*)d_in[4];
    const float* g1  = (const float*)d_in[5];
    const float* b1  = (const float*)d_in[6];
    const float* Wf  = (const float*)d_in[7];
    const float* bf  = (const float*)d_in[8];
    const float* g2  = (const float*)d_in[9];
    const float* b2  = (const float*)d_in[10];
    float* out = (float*)d_out;

    const int N = in_sizes[1];              // 500000
    const int G = out_size / H;             // 8192

    char* w = (char*)d_ws;
    int* counts  = (int*)w;  w += (size_t)G * sizeof(int);
    int* offsets = (int*)w;  w += (size_t)G * sizeof(int);
    int* idx     = (int*)w;  w += (size_t)N * sizeof(int);
    w = (char*)(((uintptr_t)w + 15) & ~(uintptr_t)15);
    _Float16* pooledH = (_Float16*)w; w += (size_t)G * H2 * sizeof(_Float16);
    _Float16* WpA     = (_Float16*)w; w += (size_t)H2 * H * sizeof(_Float16);
    _Float16* WfsA    = (_Float16*)w; w += (size_t)H * H * sizeof(_Float16);

    hipLaunchKernelGGL(k_prep, dim3(128), dim3(256), 0, stream, Wp, Wf, WpA, WfsA, counts, G);
    {
        const int* fid_p = fid;
        int Nv = N, Gv = G;
        void* args[] = { (void*)&fid_p, (void*)&counts, (void*)&offsets,
                         (void*)&idx, (void*)&Nv, (void*)&Gv };
        hipLaunchCooperativeKernel((const void*)k_sort, dim3(SORT_NB), dim3(SORT_TPB),
                                   args, 0, stream);
    }
    hipLaunchKernelGGL(k_reduce, dim3(G / 4), dim3(256), 0, stream,
                       x, idx, offsets, counts, pooledH, G);
    hipLaunchKernelGGL(k_mlp, dim3(G / ROWS), dim3(256), 0, stream,
                       pooledH, WpA, bp, g1, b1, WfsA, bf, g2, b2, out, G);
}

// Round 5
// 170.522 us; speedup vs baseline: 2.2796x; 2.2796x over previous
//
#include <hip/hip_runtime.h>

#define H    256
#define H2   512
#define ROWS 16
#define LN_EPS 1e-5f

typedef _Float16 half4v __attribute__((ext_vector_type(4)));
typedef float    f32x4  __attribute__((ext_vector_type(4)));

// ---------------- prep: zero counts + build fragment-ordered f16 weights ----------------
// WpA layout: quad q = ((kb16*16 + nb)*64 + lane); element j of quad = Wp[k][n]
// with k = kb16*16 + 4*(lane>>4) + j, n = nb*16 + (lane&15).  (A-fragment order for
// v_mfma_f32_16x16x16_f16 with A = W^T tile; mapping verified by round-3 pass.)

__global__ __launch_bounds__(256) void k_prep(const float* __restrict__ Wp,
        const float* __restrict__ Wf, _Float16* __restrict__ WpA,
        _Float16* __restrict__ WfsA, int* __restrict__ counts, int G) {
    const int tid = blockIdx.x * 256 + threadIdx.x;
    const int stride = gridDim.x * 256;
    for (int i = tid; i < G; i += stride) counts[i] = 0;
    for (int q = tid; q < 32 * 16 * 64; q += stride) {          // GEMM1: K=512 -> 32 kb16
        const int l  = q & 63;
        const int nb = (q >> 6) & 15;
        const int kb = q >> 10;
        const int n  = nb * 16 + (l & 15);
        const int k  = kb * 16 + 4 * (l >> 4);
        half4v v;
        v[0] = (_Float16)Wp[(size_t)(k + 0) * H + n];
        v[1] = (_Float16)Wp[(size_t)(k + 1) * H + n];
        v[2] = (_Float16)Wp[(size_t)(k + 2) * H + n];
        v[3] = (_Float16)Wp[(size_t)(k + 3) * H + n];
        *(half4v*)&WpA[(size_t)q * 4] = v;
    }
    for (int q = tid; q < 16 * 16 * 64; q += stride) {          // GEMM2: K=256, Wf folded 3->1
        const int l  = q & 63;
        const int nb = (q >> 6) & 15;
        const int kb = q >> 10;
        const int n  = nb * 16 + (l & 15);
        const int k  = kb * 16 + 4 * (l >> 4);
        half4v v;
        #pragma unroll
        for (int j = 0; j < 4; ++j) {
            const int kj = k + j;
            v[j] = (_Float16)(Wf[(size_t)kj * H + n] + Wf[(size_t)(kj + H) * H + n]
                              + Wf[(size_t)(kj + 2 * H) * H + n]);
        }
        *(half4v*)&WfsA[(size_t)q * 4] = v;
    }
}

// ---------------- counting sort (non-cooperative 3-kernel chain) ----------------

__global__ void k_hist_rank(const int* __restrict__ fid, int* __restrict__ counts,
                            int* __restrict__ rank, int N) {
    int i = blockIdx.x * blockDim.x + threadIdx.x;
    int stride = gridDim.x * blockDim.x;
    for (; i < N; i += stride) rank[i] = atomicAdd(&counts[fid[i]], 1);
}

__global__ __launch_bounds__(1024) void k_scan(const int* __restrict__ counts,
                                               int* __restrict__ offsets, int G) {
    __shared__ int part[1024];
    const int t = threadIdx.x;
    const int per = (G + 1023) / 1024;
    const int base = t * per;
    int local[16];
    int s = 0;
    for (int j = 0; j < per; ++j) {
        int v = (base + j < G) ? counts[base + j] : 0;
        local[j] = s;
        s += v;
    }
    part[t] = s;
    __syncthreads();
    for (int off = 1; off < 1024; off <<= 1) {
        int v = 0;
        if (t >= off) v = part[t - off];
        __syncthreads();
        part[t] += v;
        __syncthreads();
    }
    int tbase = (t == 0) ? 0 : part[t - 1];
    for (int j = 0; j < per; ++j)
        if (base + j < G) offsets[base + j] = tbase + local[j];
}

__global__ void k_scatter(const int* __restrict__ fid, const int* __restrict__ rank,
                          const int* __restrict__ offsets,
                          int* __restrict__ idx_sorted, int N) {
    int i = blockIdx.x * blockDim.x + threadIdx.x;
    int stride = gridDim.x * blockDim.x;
    for (; i < N; i += stride)
        idx_sorted[offsets[fid[i]] + rank[i]] = i;
}

// ---------------- segment mean+max gather (1 wave/group, idx prefetch, f16 out) ----------------

__global__ __launch_bounds__(256) void k_reduce(const float* __restrict__ x,
        const int* __restrict__ idx, const int* __restrict__ offsets,
        const int* __restrict__ counts, _Float16* __restrict__ pooledH, int G) {
    int g = __builtin_amdgcn_readfirstlane(blockIdx.x * 4 + (threadIdx.x >> 6));
    if (g >= G) return;
    const int t = threadIdx.x & 63;
    const int start = offsets[g];
    const int cnt   = counts[g];
    const float4* __restrict__ xv = (const float4*)x;

    float4 s = make_float4(0.f, 0.f, 0.f, 0.f);
    const float ninf = -__builtin_inff();
    float4 m = make_float4(ninf, ninf, ninf, ninf);

    int j = 0;
    if (cnt >= 4) {
        int p0 = idx[start + 0], p1 = idx[start + 1];
        int p2 = idx[start + 2], p3 = idx[start + 3];
        for (; j + 8 <= cnt; j += 4) {
            const int c0 = p0, c1 = p1, c2 = p2, c3 = p3;
            p0 = idx[start + j + 4]; p1 = idx[start + j + 5];
            p2 = idx[start + j + 6]; p3 = idx[start + j + 7];
            float4 a = xv[(size_t)c0 * 64 + t];
            float4 b = xv[(size_t)c1 * 64 + t];
            float4 c = xv[(size_t)c2 * 64 + t];
            float4 d = xv[(size_t)c3 * 64 + t];
            s.x += (a.x + b.x) + (c.x + d.x);
            s.y += (a.y + b.y) + (c.y + d.y);
            s.z += (a.z + b.z) + (c.z + d.z);
            s.w += (a.w + b.w) + (c.w + d.w);
            m.x = fmaxf(m.x, fmaxf(fmaxf(a.x, b.x), fmaxf(c.x, d.x)));
            m.y = fmaxf(m.y, fmaxf(fmaxf(a.y, b.y), fmaxf(c.y, d.y)));
            m.z = fmaxf(m.z, fmaxf(fmaxf(a.z, b.z), fmaxf(c.z, d.z)));
            m.w = fmaxf(m.w, fmaxf(fmaxf(a.w, b.w), fmaxf(c.w, d.w)));
        }
        {   // consume last prefetched quartet
            float4 a = xv[(size_t)p0 * 64 + t];
            float4 b = xv[(size_t)p1 * 64 + t];
            float4 c = xv[(size_t)p2 * 64 + t];
            float4 d = xv[(size_t)p3 * 64 + t];
            s.x += (a.x + b.x) + (c.x + d.x);
            s.y += (a.y + b.y) + (c.y + d.y);
            s.z += (a.z + b.z) + (c.z + d.z);
            s.w += (a.w + b.w) + (c.w + d.w);
            m.x = fmaxf(m.x, fmaxf(fmaxf(a.x, b.x), fmaxf(c.x, d.x)));
            m.y = fmaxf(m.y, fmaxf(fmaxf(a.y, b.y), fmaxf(c.y, d.y)));
            m.z = fmaxf(m.z, fmaxf(fmaxf(a.z, b.z), fmaxf(c.z, d.z)));
            m.w = fmaxf(m.w, fmaxf(fmaxf(a.w, b.w), fmaxf(c.w, d.w)));
            j += 4;
        }
    }
    for (; j < cnt; ++j) {
        int i0 = idx[start + j];
        float4 a = xv[(size_t)i0 * 64 + t];
        s.x += a.x; s.y += a.y; s.z += a.z; s.w += a.w;
        m.x = fmaxf(m.x, a.x); m.y = fmaxf(m.y, a.y);
        m.z = fmaxf(m.z, a.z); m.w = fmaxf(m.w, a.w);
    }
    const float inv = 1.0f / (float)((cnt > 1) ? cnt : 1);
    half4v mh, xh;
    mh[0] = (_Float16)(s.x * inv); mh[1] = (_Float16)(s.y * inv);
    mh[2] = (_Float16)(s.z * inv); mh[3] = (_Float16)(s.w * inv);
    xh[0] = (_Float16)m.x; xh[1] = (_Float16)m.y;
    xh[2] = (_Float16)m.z; xh[3] = (_Float16)m.w;
    *(half4v*)&pooledH[(size_t)g * H2 + 4 * t]     = mh;   // mean -> cols [0,256)
    *(half4v*)&pooledH[(size_t)g * H2 + H + 4 * t] = xh;   // max  -> cols [256,512)
}

// ---------------- fused MLP, MFMA f16, fragment-ordered LDS (all b64 linear) ----------------
// D^T = W^T(A) x pooled^T(B). Lane l, reg r of fragment (nb): row m = l&15,
// col n = nb*16 + 4*(l>>4) + r. LN1 output writes land exactly on GEMM2 B slots.

__global__ __launch_bounds__(256) void k_mlp(const _Float16* __restrict__ pooledH,
        const _Float16* __restrict__ WpA, const float* __restrict__ bp,
        const float* __restrict__ g1, const float* __restrict__ b1,
        const _Float16* __restrict__ WfsA, const float* __restrict__ bf,
        const float* __restrict__ g2, const float* __restrict__ b2,
        float* __restrict__ out, int G) {
    __shared__ _Float16 spB[32 * 64 * 4];   // 16 KB: pooled B-fragments (32 kb16)
    __shared__ _Float16 sA[4 * 16 * 64 * 4];// 32 KB: weight A-fragment tile (4 kb16 x 16 nb)
    __shared__ _Float16 sfB[16 * 64 * 4];   //  8 KB: func B-fragments (16 kb16)
    __shared__ float red[4][16][2];

    const int t   = threadIdx.x;
    const int l   = t & 63;
    const int w   = t >> 6;
    const int li  = l & 15;
    const int grp = l >> 4;
    const int g0  = blockIdx.x * ROWS;

    // stage pooled rows into fragment-ordered spB (b64 linear LDS writes)
    #pragma unroll
    for (int jj = 0; jj < 8; ++jj) {
        const int q = t + jj * 256;
        const int kb16 = q >> 6, ll = q & 63;
        *(half4v*)&spB[q * 4] =
            *(const half4v*)&pooledH[(size_t)(g0 + (ll & 15)) * H2 + kb16 * 16 + 4 * (ll >> 4)];
    }

    f32x4 acc[4];
    #pragma unroll
    for (int f = 0; f < 4; ++f) acc[f] = (f32x4)(0.f);

    // ---- GEMM1: K = 512, tiles of 64
    for (int k0 = 0; k0 < H2; k0 += 64) {
        {
            const int4* src = (const int4*)WpA + (size_t)(k0 >> 4) * 512;
            int4* dst = (int4*)sA;
            #pragma unroll
            for (int jj = 0; jj < 8; ++jj) dst[t + jj * 256] = src[t + jj * 256];
        }
        __syncthreads();
        #pragma unroll
        for (int kb = 0; kb < 4; ++kb) {
            half4v bfrag = *(const half4v*)&spB[(((k0 >> 4) + kb) * 64 + l) * 4];
            #pragma unroll
            for (int f = 0; f < 4; ++f) {
                const int nb = 4 * w + f;
                half4v afrag = *(const half4v*)&sA[((kb * 16 + nb) * 64 + l) * 4];
                acc[f] = __builtin_amdgcn_mfma_f32_16x16x16f16(afrag, bfrag, acc[f], 0, 0, 0);
            }
        }
        __syncthreads();
    }

    // ---- bias + LN1 + ReLU -> sfB (writes are this lane's own GEMM2 B slots)
    {
        f32x4 vv[4], g1v[4], b1v[4];
        float sum = 0.f, sq = 0.f;
        #pragma unroll
        for (int f = 0; f < 4; ++f) {
            const int n0 = 64 * w + 16 * f + 4 * grp;
            f32x4 bb = *(const f32x4*)&bp[n0];
            g1v[f] = *(const f32x4*)&g1[n0];
            b1v[f] = *(const f32x4*)&b1[n0];
            #pragma unroll
            for (int r = 0; r < 4; ++r) {
                float v = acc[f][r] + bb[r];
                vv[f][r] = v;
                sum += v; sq += v * v;
            }
        }
        sum += __shfl_xor(sum, 16, 64); sq += __shfl_xor(sq, 16, 64);
        sum += __shfl_xor(sum, 32, 64); sq += __shfl_xor(sq, 32, 64);
        if (grp == 0) { red[w][li][0] = sum; red[w][li][1] = sq; }
        __syncthreads();
        const float S = red[0][li][0] + red[1][li][0] + red[2][li][0] + red[3][li][0];
        const float Q = red[0][li][1] + red[1][li][1] + red[2][li][1] + red[3][li][1];
        const float mu  = S * (1.0f / H);
        const float var = Q * (1.0f / H) - mu * mu;
        const float rs  = rsqrtf(var + LN_EPS);
        #pragma unroll
        for (int f = 0; f < 4; ++f) {
            half4v hv;
            #pragma unroll
            for (int r = 0; r < 4; ++r)
                hv[r] = (_Float16)fmaxf((vv[f][r] - mu) * rs * g1v[f][r] + b1v[f][r], 0.f);
            *(half4v*)&sfB[((4 * w + f) * 64 + l) * 4] = hv;
        }
    }

    // ---- GEMM2: K = 256, tiles of 64
    f32x4 acc2[4];
    #pragma unroll
    for (int f = 0; f < 4; ++f) acc2[f] = (f32x4)(0.f);

    for (int k0 = 0; k0 < H; k0 += 64) {
        {
            const int4* src = (const int4*)WfsA + (size_t)(k0 >> 4) * 512;
            int4* dst = (int4*)sA;
            #pragma unroll
            for (int jj = 0; jj < 8; ++jj) dst[t + jj * 256] = src[t + jj * 256];
        }
        __syncthreads();
        #pragma unroll
        for (int kb = 0; kb < 4; ++kb) {
            half4v bfrag = *(const half4v*)&sfB[(((k0 >> 4) + kb) * 64 + l) * 4];
            #pragma unroll
            for (int f = 0; f < 4; ++f) {
                const int nb = 4 * w + f;
                half4v afrag = *(const half4v*)&sA[((kb * 16 + nb) * 64 + l) * 4];
                acc2[f] = __builtin_amdgcn_mfma_f32_16x16x16f16(afrag, bfrag, acc2[f], 0, 0, 0);
            }
        }
        __syncthreads();
    }

    // ---- bias + LN2 + ReLU -> out
    {
        f32x4 vv[4], g2v[4], b2v[4];
        float sum = 0.f, sq = 0.f;
        #pragma unroll
        for (int f = 0; f < 4; ++f) {
            const int n0 = 64 * w + 16 * f + 4 * grp;
            f32x4 bb = *(const f32x4*)&bf[n0];
            g2v[f] = *(const f32x4*)&g2[n0];
            b2v[f] = *(const f32x4*)&b2[n0];
            #pragma unroll
            for (int r = 0; r < 4; ++r) {
                float v = acc2[f][r] + bb[r];
                vv[f][r] = v;
                sum += v; sq += v * v;
            }
        }
        sum += __shfl_xor(sum, 16, 64); sq += __shfl_xor(sq, 16, 64);
        sum += __shfl_xor(sum, 32, 64); sq += __shfl_xor(sq, 32, 64);
        if (grp == 0) { red[w][li][0] = sum; red[w][li][1] = sq; }
        __syncthreads();
        const float S = red[0][li][0] + red[1][li][0] + red[2][li][0] + red[3][li][0];
        const float Q = red[0][li][1] + red[1][li][1] + red[2][li][1] + red[3][li][1];
        const float mu  = S * (1.0f / H);
        const float var = Q * (1.0f / H) - mu * mu;
        const float rs  = rsqrtf(var + LN_EPS);
        const int grow = g0 + li;
        #pragma unroll
        for (int f = 0; f < 4; ++f) {
            const int n0 = 64 * w + 16 * f + 4 * grp;
            f32x4 o;
            #pragma unroll
            for (int r = 0; r < 4; ++r)
                o[r] = fmaxf((vv[f][r] - mu) * rs * g2v[f][r] + b2v[f][r], 0.f);
            if (grow < G) *(f32x4*)&out[(size_t)grow * H + n0] = o;
        }
    }
}

// ---------------- launch ----------------

extern "C" void kernel_launch(void* const* d_in, const int* in_sizes, int n_in,
                              void* d_out, int out_size, void* d_ws, size_t ws_size,
                              hipStream_t stream) {
    const float* x   = (const float*)d_in[0];
    const int*   fid = (const int*)d_in[2];
    const float* Wp  = (const float*)d_in[3];
    const float* bp  = (const float*)d_in[4];
    const float* g1  = (const float*)d_in[5];
    const float* b1  = (const float*)d_in[6];
    const float* Wf  = (const float*)d_in[7];
    const float* bf  = (const float*)d_in[8];
    const float* g2  = (const float*)d_in[9];
    const float* b2  = (const float*)d_in[10];
    float* out = (float*)d_out;

    const int N = in_sizes[1];              // 500000
    const int G = out_size / H;             // 8192

    char* w = (char*)d_ws;
    int* counts  = (int*)w;  w += (size_t)G * sizeof(int);
    int* offsets = (int*)w;  w += (size_t)G * sizeof(int);
    int* rank    = (int*)w;  w += (size_t)N * sizeof(int);
    int* idx     = (int*)w;  w += (size_t)N * sizeof(int);
    w = (char*)(((uintptr_t)w + 15) & ~(uintptr_t)15);
    _Float16* pooledH = (_Float16*)w; w += (size_t)G * H2 * sizeof(_Float16);
    _Float16* WpA     = (_Float16*)w; w += (size_t)H2 * H * sizeof(_Float16);
    _Float16* WfsA    = (_Float16*)w; w += (size_t)H * H * sizeof(_Float16);

    hipLaunchKernelGGL(k_prep,      dim3(128), dim3(256), 0, stream, Wp, Wf, WpA, WfsA, counts, G);
    hipLaunchKernelGGL(k_hist_rank, dim3(1024), dim3(256), 0, stream, fid, counts, rank, N);
    hipLaunchKernelGGL(k_scan,      dim3(1), dim3(1024), 0, stream, counts, offsets, G);
    hipLaunchKernelGGL(k_scatter,   dim3(1024), dim3(256), 0, stream, fid, rank, offsets, idx, N);
    hipLaunchKernelGGL(k_reduce,    dim3(G / 4), dim3(256), 0, stream,
                       x, idx, offsets, counts, pooledH, G);
    hipLaunchKernelGGL(k_mlp,       dim3(G / ROWS), dim3(256), 0, stream,
                       pooledH, WpA, bp, g1, b1, WfsA, bf, g2, b2, out, G);
}

// Round 6
// 168.628 us; speedup vs baseline: 2.3052x; 1.0112x over previous
//
#include <hip/hip_runtime.h>

#define H    256
#define H2   512
#define ROWS 16
#define LN_EPS 1e-5f

typedef _Float16 half4v __attribute__((ext_vector_type(4)));
typedef float    f32x4  __attribute__((ext_vector_type(4)));

// ---------------- prep: zero counts + build fragment-ordered f16 weights ----------------
// WpA layout: quad q = ((kb16*16 + nb)*64 + lane); element j of quad = Wp[k][n]
// with k = kb16*16 + 4*(lane>>4) + j, n = nb*16 + (lane&15).  (A-fragment order for
// v_mfma_f32_16x16x16_f16 with A = W^T tile; mapping verified by round-3 pass.)

__global__ __launch_bounds__(256) void k_prep(const float* __restrict__ Wp,
        const float* __restrict__ Wf, _Float16* __restrict__ WpA,
        _Float16* __restrict__ WfsA, int* __restrict__ counts, int G) {
    const int tid = blockIdx.x * 256 + threadIdx.x;
    const int stride = gridDim.x * 256;
    for (int i = tid; i < G; i += stride) counts[i] = 0;
    for (int q = tid; q < 32 * 16 * 64; q += stride) {          // GEMM1: K=512 -> 32 kb16
        const int l  = q & 63;
        const int nb = (q >> 6) & 15;
        const int kb = q >> 10;
        const int n  = nb * 16 + (l & 15);
        const int k  = kb * 16 + 4 * (l >> 4);
        half4v v;
        v[0] = (_Float16)Wp[(size_t)(k + 0) * H + n];
        v[1] = (_Float16)Wp[(size_t)(k + 1) * H + n];
        v[2] = (_Float16)Wp[(size_t)(k + 2) * H + n];
        v[3] = (_Float16)Wp[(size_t)(k + 3) * H + n];
        *(half4v*)&WpA[(size_t)q * 4] = v;
    }
    for (int q = tid; q < 16 * 16 * 64; q += stride) {          // GEMM2: K=256, Wf folded 3->1
        const int l  = q & 63;
        const int nb = (q >> 6) & 15;
        const int kb = q >> 10;
        const int n  = nb * 16 + (l & 15);
        const int k  = kb * 16 + 4 * (l >> 4);
        half4v v;
        #pragma unroll
        for (int j = 0; j < 4; ++j) {
            const int kj = k + j;
            v[j] = (_Float16)(Wf[(size_t)kj * H + n] + Wf[(size_t)(kj + H) * H + n]
                              + Wf[(size_t)(kj + 2 * H) * H + n]);
        }
        *(half4v*)&WfsA[(size_t)q * 4] = v;
    }
}

// ---------------- counting sort (non-cooperative 3-kernel chain) ----------------

__global__ void k_hist_rank(const int* __restrict__ fid, int* __restrict__ counts,
                            int* __restrict__ rank, int N) {
    int i = blockIdx.x * blockDim.x + threadIdx.x;
    int stride = gridDim.x * blockDim.x;
    for (; i < N; i += stride) rank[i] = atomicAdd(&counts[fid[i]], 1);
}

// 256-thread shuffle scan over G counters (logic verified in round 4)
__global__ __launch_bounds__(256) void k_scan(const int* __restrict__ counts,
                                              int* __restrict__ offsets, int G) {
    __shared__ int wsum[4];
    const int tt = threadIdx.x;
    const int lane = tt & 63, ww = tt >> 6;
    const int base = tt * 32;
    int pre[32];
    int s = 0;
    if (base + 32 <= G) {
        #pragma unroll
        for (int j = 0; j < 32; j += 4) {
            int4 c = *(const int4*)&counts[base + j];
            pre[j]     = s; s += c.x;
            pre[j + 1] = s; s += c.y;
            pre[j + 2] = s; s += c.z;
            pre[j + 3] = s; s += c.w;
        }
    } else {
        #pragma unroll
        for (int j = 0; j < 32; ++j) {
            int c = (base + j < G) ? counts[base + j] : 0;
            pre[j] = s; s += c;
        }
    }
    int inc = s;
    #pragma unroll
    for (int off = 1; off < 64; off <<= 1) {
        int u = __shfl_up(inc, off, 64);
        if (lane >= off) inc += u;
    }
    if (lane == 63) wsum[ww] = inc;
    __syncthreads();
    int wb = 0;
    #pragma unroll
    for (int i = 0; i < 4; ++i) wb += (i < ww) ? wsum[i] : 0;
    const int tb = wb + inc - s;                // exclusive base for this thread
    if (base + 32 <= G) {
        #pragma unroll
        for (int j = 0; j < 32; j += 4) {
            int4 o = make_int4(tb + pre[j], tb + pre[j + 1], tb + pre[j + 2], tb + pre[j + 3]);
            *(int4*)&offsets[base + j] = o;
        }
    } else {
        for (int j = 0; j < 32; ++j)
            if (base + j < G) offsets[base + j] = tb + pre[j];
    }
}

__global__ void k_scatter(const int* __restrict__ fid, const int* __restrict__ rank,
                          const int* __restrict__ offsets,
                          int* __restrict__ idx_sorted, int N) {
    int i = blockIdx.x * blockDim.x + threadIdx.x;
    int stride = gridDim.x * blockDim.x;
    for (; i < N; i += stride)
        idx_sorted[offsets[fid[i]] + rank[i]] = i;
}

// ---------------- segment mean+max gather ----------------
// 1 wave/group. Per 64-row chunk: ONE coalesced idx load (idx[start+base+t]),
// then __shfl(lidx, j) broadcasts (v_readlane -> SGPR saddr). All row addresses
// in the chunk are independent of loads -> 8 row-loads kept in flight.

__global__ __launch_bounds__(256) void k_reduce(const float* __restrict__ x,
        const int* __restrict__ idx, const int* __restrict__ offsets,
        const int* __restrict__ counts, _Float16* __restrict__ pooledH, int G) {
    const int g = blockIdx.x * 4 + (threadIdx.x >> 6);
    if (g >= G) return;
    const int t = threadIdx.x & 63;
    const int start = offsets[g];
    const int cnt   = counts[g];
    const float4* __restrict__ xv = (const float4*)x;

    float4 s = make_float4(0.f, 0.f, 0.f, 0.f);
    const float ninf = -__builtin_inff();
    float4 m = make_float4(ninf, ninf, ninf, ninf);

    for (int base = 0; base < cnt; base += 64) {
        const int rem = min(cnt - base, 64);
        const int lidx = idx[start + base + ((t < rem) ? t : (rem - 1))];
        int j = 0;
        for (; j + 8 <= rem; j += 8) {
            float4 r0 = xv[(size_t)__shfl(lidx, j + 0, 64) * 64 + t];
            float4 r1 = xv[(size_t)__shfl(lidx, j + 1, 64) * 64 + t];
            float4 r2 = xv[(size_t)__shfl(lidx, j + 2, 64) * 64 + t];
            float4 r3 = xv[(size_t)__shfl(lidx, j + 3, 64) * 64 + t];
            float4 r4 = xv[(size_t)__shfl(lidx, j + 4, 64) * 64 + t];
            float4 r5 = xv[(size_t)__shfl(lidx, j + 5, 64) * 64 + t];
            float4 r6 = xv[(size_t)__shfl(lidx, j + 6, 64) * 64 + t];
            float4 r7 = xv[(size_t)__shfl(lidx, j + 7, 64) * 64 + t];
            s.x += ((r0.x + r1.x) + (r2.x + r3.x)) + ((r4.x + r5.x) + (r6.x + r7.x));
            s.y += ((r0.y + r1.y) + (r2.y + r3.y)) + ((r4.y + r5.y) + (r6.y + r7.y));
            s.z += ((r0.z + r1.z) + (r2.z + r3.z)) + ((r4.z + r5.z) + (r6.z + r7.z));
            s.w += ((r0.w + r1.w) + (r2.w + r3.w)) + ((r4.w + r5.w) + (r6.w + r7.w));
            m.x = fmaxf(m.x, fmaxf(fmaxf(fmaxf(r0.x, r1.x), fmaxf(r2.x, r3.x)),
                                   fmaxf(fmaxf(r4.x, r5.x), fmaxf(r6.x, r7.x))));
            m.y = fmaxf(m.y, fmaxf(fmaxf(fmaxf(r0.y, r1.y), fmaxf(r2.y, r3.y)),
                                   fmaxf(fmaxf(r4.y, r5.y), fmaxf(r6.y, r7.y))));
            m.z = fmaxf(m.z, fmaxf(fmaxf(fmaxf(r0.z, r1.z), fmaxf(r2.z, r3.z)),
                                   fmaxf(fmaxf(r4.z, r5.z), fmaxf(r6.z, r7.z))));
            m.w = fmaxf(m.w, fmaxf(fmaxf(fmaxf(r0.w, r1.w), fmaxf(r2.w, r3.w)),
                                   fmaxf(fmaxf(r4.w, r5.w), fmaxf(r6.w, r7.w))));
        }
        for (; j < rem; ++j) {
            float4 a = xv[(size_t)__shfl(lidx, j, 64) * 64 + t];
            s.x += a.x; s.y += a.y; s.z += a.z; s.w += a.w;
            m.x = fmaxf(m.x, a.x); m.y = fmaxf(m.y, a.y);
            m.z = fmaxf(m.z, a.z); m.w = fmaxf(m.w, a.w);
        }
    }
    const float inv = 1.0f / (float)((cnt > 1) ? cnt : 1);
    half4v mh, xh;
    mh[0] = (_Float16)(s.x * inv); mh[1] = (_Float16)(s.y * inv);
    mh[2] = (_Float16)(s.z * inv); mh[3] = (_Float16)(s.w * inv);
    xh[0] = (_Float16)m.x; xh[1] = (_Float16)m.y;
    xh[2] = (_Float16)m.z; xh[3] = (_Float16)m.w;
    *(half4v*)&pooledH[(size_t)g * H2 + 4 * t]     = mh;   // mean -> cols [0,256)
    *(half4v*)&pooledH[(size_t)g * H2 + H + 4 * t] = xh;   // max  -> cols [256,512)
}

// ---------------- fused MLP, MFMA f16, fragment-ordered LDS (all b64 linear) ----------------
// D^T = W^T(A) x pooled^T(B). Lane l, reg r of fragment (nb): row m = l&15,
// col n = nb*16 + 4*(l>>4) + r. LN1 output writes land exactly on GEMM2 B slots.

__global__ __launch_bounds__(256) void k_mlp(const _Float16* __restrict__ pooledH,
        const _Float16* __restrict__ WpA, const float* __restrict__ bp,
        const float* __restrict__ g1, const float* __restrict__ b1,
        const _Float16* __restrict__ WfsA, const float* __restrict__ bf,
        const float* __restrict__ g2, const float* __restrict__ b2,
        float* __restrict__ out, int G) {
    __shared__ _Float16 spB[32 * 64 * 4];   // 16 KB: pooled B-fragments (32 kb16)
    __shared__ _Float16 sA[4 * 16 * 64 * 4];// 32 KB: weight A-fragment tile (4 kb16 x 16 nb)
    __shared__ _Float16 sfB[16 * 64 * 4];   //  8 KB: func B-fragments (16 kb16)
    __shared__ float red[4][16][2];

    const int t   = threadIdx.x;
    const int l   = t & 63;
    const int w   = t >> 6;
    const int li  = l & 15;
    const int grp = l >> 4;
    const int g0  = blockIdx.x * ROWS;

    // stage pooled rows into fragment-ordered spB (b64 linear LDS writes)
    #pragma unroll
    for (int jj = 0; jj < 8; ++jj) {
        const int q = t + jj * 256;
        const int kb16 = q >> 6, ll = q & 63;
        *(half4v*)&spB[q * 4] =
            *(const half4v*)&pooledH[(size_t)(g0 + (ll & 15)) * H2 + kb16 * 16 + 4 * (ll >> 4)];
    }

    f32x4 acc[4];
    #pragma unroll
    for (int f = 0; f < 4; ++f) acc[f] = (f32x4)(0.f);

    // ---- GEMM1: K = 512, tiles of 64
    for (int k0 = 0; k0 < H2; k0 += 64) {
        {
            const int4* src = (const int4*)WpA + (size_t)(k0 >> 4) * 512;
            int4* dst = (int4*)sA;
            #pragma unroll
            for (int jj = 0; jj < 8; ++jj) dst[t + jj * 256] = src[t + jj * 256];
        }
        __syncthreads();
        #pragma unroll
        for (int kb = 0; kb < 4; ++kb) {
            half4v bfrag = *(const half4v*)&spB[(((k0 >> 4) + kb) * 64 + l) * 4];
            #pragma unroll
            for (int f = 0; f < 4; ++f) {
                const int nb = 4 * w + f;
                half4v afrag = *(const half4v*)&sA[((kb * 16 + nb) * 64 + l) * 4];
                acc[f] = __builtin_amdgcn_mfma_f32_16x16x16f16(afrag, bfrag, acc[f], 0, 0, 0);
            }
        }
        __syncthreads();
    }

    // ---- bias + LN1 + ReLU -> sfB (writes are this lane's own GEMM2 B slots)
    {
        f32x4 vv[4], g1v[4], b1v[4];
        float sum = 0.f, sq = 0.f;
        #pragma unroll
        for (int f = 0; f < 4; ++f) {
            const int n0 = 64 * w + 16 * f + 4 * grp;
            f32x4 bb = *(const f32x4*)&bp[n0];
            g1v[f] = *(const f32x4*)&g1[n0];
            b1v[f] = *(const f32x4*)&b1[n0];
            #pragma unroll
            for (int r = 0; r < 4; ++r) {
                float v = acc[f][r] + bb[r];
                vv[f][r] = v;
                sum += v; sq += v * v;
            }
        }
        sum += __shfl_xor(sum, 16, 64); sq += __shfl_xor(sq, 16, 64);
        sum += __shfl_xor(sum, 32, 64); sq += __shfl_xor(sq, 32, 64);
        if (grp == 0) { red[w][li][0] = sum; red[w][li][1] = sq; }
        __syncthreads();
        const float S = red[0][li][0] + red[1][li][0] + red[2][li][0] + red[3][li][0];
        const float Q = red[0][li][1] + red[1][li][1] + red[2][li][1] + red[3][li][1];
        const float mu  = S * (1.0f / H);
        const float var = Q * (1.0f / H) - mu * mu;
        const float rs  = rsqrtf(var + LN_EPS);
        #pragma unroll
        for (int f = 0; f < 4; ++f) {
            half4v hv;
            #pragma unroll
            for (int r = 0; r < 4; ++r)
                hv[r] = (_Float16)fmaxf((vv[f][r] - mu) * rs * g1v[f][r] + b1v[f][r], 0.f);
            *(half4v*)&sfB[((4 * w + f) * 64 + l) * 4] = hv;
        }
    }

    // ---- GEMM2: K = 256, tiles of 64
    f32x4 acc2[4];
    #pragma unroll
    for (int f = 0; f < 4; ++f) acc2[f] = (f32x4)(0.f);

    for (int k0 = 0; k0 < H; k0 += 64) {
        {
            const int4* src = (const int4*)WfsA + (size_t)(k0 >> 4) * 512;
            int4* dst = (int4*)sA;
            #pragma unroll
            for (int jj = 0; jj < 8; ++jj) dst[t + jj * 256] = src[t + jj * 256];
        }
        __syncthreads();
        #pragma unroll
        for (int kb = 0; kb < 4; ++kb) {
            half4v bfrag = *(const half4v*)&sfB[(((k0 >> 4) + kb) * 64 + l) * 4];
            #pragma unroll
            for (int f = 0; f < 4; ++f) {
                const int nb = 4 * w + f;
                half4v afrag = *(const half4v*)&sA[((kb * 16 + nb) * 64 + l) * 4];
                acc2[f] = __builtin_amdgcn_mfma_f32_16x16x16f16(afrag, bfrag, acc2[f], 0, 0, 0);
            }
        }
        __syncthreads();
    }

    // ---- bias + LN2 + ReLU -> out
    {
        f32x4 vv[4], g2v[4], b2v[4];
        float sum = 0.f, sq = 0.f;
        #pragma unroll
        for (int f = 0; f < 4; ++f) {
            const int n0 = 64 * w + 16 * f + 4 * grp;
            f32x4 bb = *(const f32x4*)&bf[n0];
            g2v[f] = *(const f32x4*)&g2[n0];
            b2v[f] = *(const f32x4*)&b2[n0];
            #pragma unroll
            for (int r = 0; r < 4; ++r) {
                float v = acc2[f][r] + bb[r];
                vv[f][r] = v;
                sum += v; sq += v * v;
            }
        }
        sum += __shfl_xor(sum, 16, 64); sq += __shfl_xor(sq, 16, 64);
        sum += __shfl_xor(sum, 32, 64); sq += __shfl_xor(sq, 32, 64);
        if (grp == 0) { red[w][li][0] = sum; red[w][li][1] = sq; }
        __syncthreads();
        const float S = red[0][li][0] + red[1][li][0] + red[2][li][0] + red[3][li][0];
        const float Q = red[0][li][1] + red[1][li][1] + red[2][li][1] + red[3][li][1];
        const float mu  = S * (1.0f / H);
        const float var = Q * (1.0f / H) - mu * mu;
        const float rs  = rsqrtf(var + LN_EPS);
        const int grow = g0 + li;
        #pragma unroll
        for (int f = 0; f < 4; ++f) {
            const int n0 = 64 * w + 16 * f + 4 * grp;
            f32x4 o;
            #pragma unroll
            for (int r = 0; r < 4; ++r)
                o[r] = fmaxf((vv[f][r] - mu) * rs * g2v[f][r] + b2v[f][r], 0.f);
            if (grow < G) *(f32x4*)&out[(size_t)grow * H + n0] = o;
        }
    }
}

// ---------------- launch ----------------

extern "C" void kernel_launch(void* const* d_in, const int* in_sizes, int n_in,
                              void* d_out, int out_size, void* d_ws, size_t ws_size,
                              hipStream_t stream) {
    const float* x   = (const float*)d_in[0];
    const int*   fid = (const int*)d_in[2];
    const float* Wp  = (const float*)d_in[3];
    const float* bp  = (const float*)d_in[4];
    const float* g1  = (const float*)d_in[5];
    const float* b1  = (const float*)d_in[6];
    const float* Wf  = (const float*)d_in[7];
    const float* bf  = (const float*)d_in[8];
    const float* g2  = (const float*)d_in[9];
    const float* b2  = (const float*)d_in[10];
    float* out = (float*)d_out;

    const int N = in_sizes[1];              // 500000
    const int G = out_size / H;             // 8192

    char* w = (char*)d_ws;
    int* counts  = (int*)w;  w += (size_t)G * sizeof(int);
    int* offsets = (int*)w;  w += (size_t)G * sizeof(int);
    int* rank    = (int*)w;  w += (size_t)N * sizeof(int);
    int* idx     = (int*)w;  w += (size_t)N * sizeof(int);
    w = (char*)(((uintptr_t)w + 15) & ~(uintptr_t)15);
    _Float16* pooledH = (_Float16*)w; w += (size_t)G * H2 * sizeof(_Float16);
    _Float16* WpA     = (_Float16*)w; w += (size_t)H2 * H * sizeof(_Float16);
    _Float16* WfsA    = (_Float16*)w; w += (size_t)H * H * sizeof(_Float16);

    hipLaunchKernelGGL(k_prep,      dim3(128), dim3(256), 0, stream, Wp, Wf, WpA, WfsA, counts, G);
    hipLaunchKernelGGL(k_hist_rank, dim3(1024), dim3(256), 0, stream, fid, counts, rank, N);
    hipLaunchKernelGGL(k_scan,      dim3(1), dim3(256), 0, stream, counts, offsets, G);
    hipLaunchKernelGGL(k_scatter,   dim3(1024), dim3(256), 0, stream, fid, rank, offsets, idx, N);
    hipLaunchKernelGGL(k_reduce,    dim3(G / 4), dim3(256), 0, stream,
                       x, idx, offsets, counts, pooledH, G);
    hipLaunchKernelGGL(k_mlp,       dim3(G / ROWS), dim3(256), 0, stream,
                       pooledH, WpA, bp, g1, b1, WfsA, bf, g2, b2, out, G);
}

// Round 8
// 150.846 us; speedup vs baseline: 2.5769x; 1.1179x over previous
//
#include <hip/hip_runtime.h>

#define H    256
#define H2   512
#define ROWS 16
#define LN_EPS 1e-5f

typedef _Float16 half4v __attribute__((ext_vector_type(4)));
typedef float    f32x4  __attribute__((ext_vector_type(4)));

// ---------------- prep: zero counts + build fragment-ordered f16 weights ----------------
// WpA layout: quad q = ((kb16*16 + nb)*64 + lane); element j of quad = Wp[k][n]
// with k = kb16*16 + 4*(lane>>4) + j, n = nb*16 + (lane&15).  (A-fragment order for
// v_mfma_f32_16x16x16_f16 with A = W^T tile; mapping verified by round-3 pass.)

__global__ __launch_bounds__(256) void k_prep(const float* __restrict__ Wp,
        const float* __restrict__ Wf, _Float16* __restrict__ WpA,
        _Float16* __restrict__ WfsA, int* __restrict__ counts, int G) {
    const int tid = blockIdx.x * 256 + threadIdx.x;
    const int stride = gridDim.x * 256;
    for (int i = tid; i < G; i += stride) counts[i] = 0;
    for (int q = tid; q < 32 * 16 * 64; q += stride) {          // GEMM1: K=512 -> 32 kb16
        const int l  = q & 63;
        const int nb = (q >> 6) & 15;
        const int kb = q >> 10;
        const int n  = nb * 16 + (l & 15);
        const int k  = kb * 16 + 4 * (l >> 4);
        half4v v;
        v[0] = (_Float16)Wp[(size_t)(k + 0) * H + n];
        v[1] = (_Float16)Wp[(size_t)(k + 1) * H + n];
        v[2] = (_Float16)Wp[(size_t)(k + 2) * H + n];
        v[3] = (_Float16)Wp[(size_t)(k + 3) * H + n];
        *(half4v*)&WpA[(size_t)q * 4] = v;
    }
    for (int q = tid; q < 16 * 16 * 64; q += stride) {          // GEMM2: K=256, Wf folded 3->1
        const int l  = q & 63;
        const int nb = (q >> 6) & 15;
        const int kb = q >> 10;
        const int n  = nb * 16 + (l & 15);
        const int k  = kb * 16 + 4 * (l >> 4);
        half4v v;
        #pragma unroll
        for (int j = 0; j < 4; ++j) {
            const int kj = k + j;
            v[j] = (_Float16)(Wf[(size_t)kj * H + n] + Wf[(size_t)(kj + H) * H + n]
                              + Wf[(size_t)(kj + 2 * H) * H + n]);
        }
        *(half4v*)&WfsA[(size_t)q * 4] = v;
    }
}

// ---------------- counting sort (non-cooperative 3-kernel chain) ----------------

__global__ void k_hist_rank(const int* __restrict__ fid, int* __restrict__ counts,
                            int* __restrict__ rank, int N) {
    int i = blockIdx.x * blockDim.x + threadIdx.x;
    int stride = gridDim.x * blockDim.x;
    for (; i < N; i += stride) rank[i] = atomicAdd(&counts[fid[i]], 1);
}

// 256-thread shuffle scan over G counters
__global__ __launch_bounds__(256) void k_scan(const int* __restrict__ counts,
                                              int* __restrict__ offsets, int G) {
    __shared__ int wsum[4];
    const int tt = threadIdx.x;
    const int lane = tt & 63, ww = tt >> 6;
    const int base = tt * 32;
    int pre[32];
    int s = 0;
    if (base + 32 <= G) {
        #pragma unroll
        for (int j = 0; j < 32; j += 4) {
            int4 c = *(const int4*)&counts[base + j];
            pre[j]     = s; s += c.x;
            pre[j + 1] = s; s += c.y;
            pre[j + 2] = s; s += c.z;
            pre[j + 3] = s; s += c.w;
        }
    } else {
        #pragma unroll
        for (int j = 0; j < 32; ++j) {
            int c = (base + j < G) ? counts[base + j] : 0;
            pre[j] = s; s += c;
        }
    }
    int inc = s;
    #pragma unroll
    for (int off = 1; off < 64; off <<= 1) {
        int u = __shfl_up(inc, off, 64);
        if (lane >= off) inc += u;
    }
    if (lane == 63) wsum[ww] = inc;
    __syncthreads();
    int wb = 0;
    #pragma unroll
    for (int i = 0; i < 4; ++i) wb += (i < ww) ? wsum[i] : 0;
    const int tb = wb + inc - s;                // exclusive base for this thread
    if (base + 32 <= G) {
        #pragma unroll
        for (int j = 0; j < 32; j += 4) {
            int4 o = make_int4(tb + pre[j], tb + pre[j + 1], tb + pre[j + 2], tb + pre[j + 3]);
            *(int4*)&offsets[base + j] = o;
        }
    } else {
        for (int j = 0; j < 32; ++j)
            if (base + j < G) offsets[base + j] = tb + pre[j];
    }
}

__global__ void k_scatter(const int* __restrict__ fid, const int* __restrict__ rank,
                          const int* __restrict__ offsets,
                          int* __restrict__ idx_sorted, int N) {
    int i = blockIdx.x * blockDim.x + threadIdx.x;
    int stride = gridDim.x * blockDim.x;
    for (; i < N; i += stride)
        idx_sorted[offsets[fid[i]] + rank[i]] = i;
}

// ---------------- segment mean+max gather ----------------
// 1 wave/group. Per 64-row chunk: ONE coalesced idx load, __shfl broadcasts.
// x rows are use-once random 1KB reads -> NON-TEMPORAL (bypass L2/L3 allocation).
// NOTE: nontemporal builtin needs clang ext-vector types, not HIP_vector_type.

__global__ __launch_bounds__(256, 4) void k_reduce(const float* __restrict__ x,
        const int* __restrict__ idx, const int* __restrict__ offsets,
        const int* __restrict__ counts, _Float16* __restrict__ pooledH, int G) {
    const int g = blockIdx.x * 4 + (threadIdx.x >> 6);
    if (g >= G) return;
    const int t = threadIdx.x & 63;
    const int start = offsets[g];
    const int cnt   = counts[g];
    const f32x4* __restrict__ xv = (const f32x4*)x;

    f32x4 s = (f32x4)(0.f);
    f32x4 m = (f32x4)(-__builtin_inff());

    for (int base = 0; base < cnt; base += 64) {
        const int rem = min(cnt - base, 64);
        const int lidx = idx[start + base + ((t < rem) ? t : (rem - 1))];
        int j = 0;
        for (; j + 8 <= rem; j += 8) {
            f32x4 r0 = __builtin_nontemporal_load(&xv[(size_t)__shfl(lidx, j + 0, 64) * 64 + t]);
            f32x4 r1 = __builtin_nontemporal_load(&xv[(size_t)__shfl(lidx, j + 1, 64) * 64 + t]);
            f32x4 r2 = __builtin_nontemporal_load(&xv[(size_t)__shfl(lidx, j + 2, 64) * 64 + t]);
            f32x4 r3 = __builtin_nontemporal_load(&xv[(size_t)__shfl(lidx, j + 3, 64) * 64 + t]);
            f32x4 r4 = __builtin_nontemporal_load(&xv[(size_t)__shfl(lidx, j + 4, 64) * 64 + t]);
            f32x4 r5 = __builtin_nontemporal_load(&xv[(size_t)__shfl(lidx, j + 5, 64) * 64 + t]);
            f32x4 r6 = __builtin_nontemporal_load(&xv[(size_t)__shfl(lidx, j + 6, 64) * 64 + t]);
            f32x4 r7 = __builtin_nontemporal_load(&xv[(size_t)__shfl(lidx, j + 7, 64) * 64 + t]);
            s += ((r0 + r1) + (r2 + r3)) + ((r4 + r5) + (r6 + r7));
            #pragma unroll
            for (int e = 0; e < 4; ++e) {
                float mm = fmaxf(fmaxf(fmaxf(r0[e], r1[e]), fmaxf(r2[e], r3[e])),
                                 fmaxf(fmaxf(r4[e], r5[e]), fmaxf(r6[e], r7[e])));
                m[e] = fmaxf(m[e], mm);
            }
        }
        for (; j < rem; ++j) {
            f32x4 a = __builtin_nontemporal_load(&xv[(size_t)__shfl(lidx, j, 64) * 64 + t]);
            s += a;
            #pragma unroll
            for (int e = 0; e < 4; ++e) m[e] = fmaxf(m[e], a[e]);
        }
    }
    const float inv = 1.0f / (float)((cnt > 1) ? cnt : 1);
    half4v mh, xh;
    mh[0] = (_Float16)(s[0] * inv); mh[1] = (_Float16)(s[1] * inv);
    mh[2] = (_Float16)(s[2] * inv); mh[3] = (_Float16)(s[3] * inv);
    xh[0] = (_Float16)m[0]; xh[1] = (_Float16)m[1];
    xh[2] = (_Float16)m[2]; xh[3] = (_Float16)m[3];
    *(half4v*)&pooledH[(size_t)g * H2 + 4 * t]     = mh;   // mean -> cols [0,256)
    *(half4v*)&pooledH[(size_t)g * H2 + H + 4 * t] = xh;   // max  -> cols [256,512)
}

// ---------------- fused MLP, MFMA f16, fragment-ordered LDS (all b64 linear) ----------------
// D^T = W^T(A) x pooled^T(B). Lane l, reg r of fragment (nb): row m = l&15,
// col n = nb*16 + 4*(l>>4) + r. LN1 output writes land exactly on GEMM2 B slots.

__global__ __launch_bounds__(256) void k_mlp(const _Float16* __restrict__ pooledH,
        const _Float16* __restrict__ WpA, const float* __restrict__ bp,
        const float* __restrict__ g1, const float* __restrict__ b1,
        const _Float16* __restrict__ WfsA, const float* __restrict__ bf,
        const float* __restrict__ g2, const float* __restrict__ b2,
        float* __restrict__ out, int G) {
    __shared__ _Float16 spB[32 * 64 * 4];   // 16 KB: pooled B-fragments (32 kb16)
    __shared__ _Float16 sA[4 * 16 * 64 * 4];// 32 KB: weight A-fragment tile (4 kb16 x 16 nb)
    __shared__ _Float16 sfB[16 * 64 * 4];   //  8 KB: func B-fragments (16 kb16)
    __shared__ float red[4][16][2];

    const int t   = threadIdx.x;
    const int l   = t & 63;
    const int w   = t >> 6;
    const int li  = l & 15;
    const int grp = l >> 4;
    const int g0  = blockIdx.x * ROWS;

    // stage pooled rows into fragment-ordered spB (b64 linear LDS writes)
    #pragma unroll
    for (int jj = 0; jj < 8; ++jj) {
        const int q = t + jj * 256;
        const int kb16 = q >> 6, ll = q & 63;
        *(half4v*)&spB[q * 4] =
            *(const half4v*)&pooledH[(size_t)(g0 + (ll & 15)) * H2 + kb16 * 16 + 4 * (ll >> 4)];
    }

    f32x4 acc[4];
    #pragma unroll
    for (int f = 0; f < 4; ++f) acc[f] = (f32x4)(0.f);

    // ---- GEMM1: K = 512, tiles of 64
    for (int k0 = 0; k0 < H2; k0 += 64) {
        {
            const int4* src = (const int4*)WpA + (size_t)(k0 >> 4) * 512;
            int4* dst = (int4*)sA;
            #pragma unroll
            for (int jj = 0; jj < 8; ++jj) dst[t + jj * 256] = src[t + jj * 256];
        }
        __syncthreads();
        #pragma unroll
        for (int kb = 0; kb < 4; ++kb) {
            half4v bfrag = *(const half4v*)&spB[(((k0 >> 4) + kb) * 64 + l) * 4];
            #pragma unroll
            for (int f = 0; f < 4; ++f) {
                const int nb = 4 * w + f;
                half4v afrag = *(const half4v*)&sA[((kb * 16 + nb) * 64 + l) * 4];
                acc[f] = __builtin_amdgcn_mfma_f32_16x16x16f16(afrag, bfrag, acc[f], 0, 0, 0);
            }
        }
        __syncthreads();
    }

    // ---- bias + LN1 + ReLU -> sfB (writes are this lane's own GEMM2 B slots)
    {
        f32x4 vv[4], g1v[4], b1v[4];
        float sum = 0.f, sq = 0.f;
        #pragma unroll
        for (int f = 0; f < 4; ++f) {
            const int n0 = 64 * w + 16 * f + 4 * grp;
            f32x4 bb = *(const f32x4*)&bp[n0];
            g1v[f] = *(const f32x4*)&g1[n0];
            b1v[f] = *(const f32x4*)&b1[n0];
            #pragma unroll
            for (int r = 0; r < 4; ++r) {
                float v = acc[f][r] + bb[r];
                vv[f][r] = v;
                sum += v; sq += v * v;
            }
        }
        sum += __shfl_xor(sum, 16, 64); sq += __shfl_xor(sq, 16, 64);
        sum += __shfl_xor(sum, 32, 64); sq += __shfl_xor(sq, 32, 64);
        if (grp == 0) { red[w][li][0] = sum; red[w][li][1] = sq; }
        __syncthreads();
        const float S = red[0][li][0] + red[1][li][0] + red[2][li][0] + red[3][li][0];
        const float Q = red[0][li][1] + red[1][li][1] + red[2][li][1] + red[3][li][1];
        const float mu  = S * (1.0f / H);
        const float var = Q * (1.0f / H) - mu * mu;
        const float rs  = rsqrtf(var + LN_EPS);
        #pragma unroll
        for (int f = 0; f < 4; ++f) {
            half4v hv;
            #pragma unroll
            for (int r = 0; r < 4; ++r)
                hv[r] = (_Float16)fmaxf((vv[f][r] - mu) * rs * g1v[f][r] + b1v[f][r], 0.f);
            *(half4v*)&sfB[((4 * w + f) * 64 + l) * 4] = hv;
        }
    }

    // ---- GEMM2: K = 256, tiles of 64
    f32x4 acc2[4];
    #pragma unroll
    for (int f = 0; f < 4; ++f) acc2[f] = (f32x4)(0.f);

    for (int k0 = 0; k0 < H; k0 += 64) {
        {
            const int4* src = (const int4*)WfsA + (size_t)(k0 >> 4) * 512;
            int4* dst = (int4*)sA;
            #pragma unroll
            for (int jj = 0; jj < 8; ++jj) dst[t + jj * 256] = src[t + jj * 256];
        }
        __syncthreads();
        #pragma unroll
        for (int kb = 0; kb < 4; ++kb) {
            half4v bfrag = *(const half4v*)&sfB[(((k0 >> 4) + kb) * 64 + l) * 4];
            #pragma unroll
            for (int f = 0; f < 4; ++f) {
                const int nb = 4 * w + f;
                half4v afrag = *(const half4v*)&sA[((kb * 16 + nb) * 64 + l) * 4];
                acc2[f] = __builtin_amdgcn_mfma_f32_16x16x16f16(afrag, bfrag, acc2[f], 0, 0, 0);
            }
        }
        __syncthreads();
    }

    // ---- bias + LN2 + ReLU -> out
    {
        f32x4 vv[4], g2v[4], b2v[4];
        float sum = 0.f, sq = 0.f;
        #pragma unroll
        for (int f = 0; f < 4; ++f) {
            const int n0 = 64 * w + 16 * f + 4 * grp;
            f32x4 bb = *(const f32x4*)&bf[n0];
            g2v[f] = *(const f32x4*)&g2[n0];
            b2v[f] = *(const f32x4*)&b2[n0];
            #pragma unroll
            for (int r = 0; r < 4; ++r) {
                float v = acc2[f][r] + bb[r];
                vv[f][r] = v;
                sum += v; sq += v * v;
            }
        }
        sum += __shfl_xor(sum, 16, 64); sq += __shfl_xor(sq, 16, 64);
        sum += __shfl_xor(sum, 32, 64); sq += __shfl_xor(sq, 32, 64);
        if (grp == 0) { red[w][li][0] = sum; red[w][li][1] = sq; }
        __syncthreads();
        const float S = red[0][li][0] + red[1][li][0] + red[2][li][0] + red[3][li][0];
        const float Q = red[0][li][1] + red[1][li][1] + red[2][li][1] + red[3][li][1];
        const float mu  = S * (1.0f / H);
        const float var = Q * (1.0f / H) - mu * mu;
        const float rs  = rsqrtf(var + LN_EPS);
        const int grow = g0 + li;
        #pragma unroll
        for (int f = 0; f < 4; ++f) {
            const int n0 = 64 * w + 16 * f + 4 * grp;
            f32x4 o;
            #pragma unroll
            for (int r = 0; r < 4; ++r)
                o[r] = fmaxf((vv[f][r] - mu) * rs * g2v[f][r] + b2v[f][r], 0.f);
            if (grow < G) *(f32x4*)&out[(size_t)grow * H + n0] = o;
        }
    }
}

// ---------------- launch ----------------

extern "C" void kernel_launch(void* const* d_in, const int* in_sizes, int n_in,
                              void* d_out, int out_size, void* d_ws, size_t ws_size,
                              hipStream_t stream) {
    const float* x   = (const float*)d_in[0];
    const int*   fid = (const int*)d_in[2];
    const float* Wp  = (const float*)d_in[3];
    const float* bp  = (const float*)d_in[4];
    const float* g1  = (const float*)d_in[5];
    const float* b1  = (const float*)d_in[6];
    const float* Wf  = (const float*)d_in[7];
    const float* bf  = (const float*)d_in[8];
    const float* g2  = (const float*)d_in[9];
    const float* b2  = (const float*)d_in[10];
    float* out = (float*)d_out;

    const int N = in_sizes[1];              // 500000
    const int G = out_size / H;             // 8192

    char* w = (char*)d_ws;
    int* counts  = (int*)w;  w += (size_t)G * sizeof(int);
    int* offsets = (int*)w;  w += (size_t)G * sizeof(int);
    int* rank    = (int*)w;  w += (size_t)N * sizeof(int);
    int* idx     = (int*)w;  w += (size_t)N * sizeof(int);
    w = (char*)(((uintptr_t)w + 15) & ~(uintptr_t)15);
    _Float16* pooledH = (_Float16*)w; w += (size_t)G * H2 * sizeof(_Float16);
    _Float16* WpA     = (_Float16*)w; w += (size_t)H2 * H * sizeof(_Float16);
    _Float16* WfsA    = (_Float16*)w; w += (size_t)H * H * sizeof(_Float16);

    hipLaunchKernelGGL(k_prep,      dim3(128), dim3(256), 0, stream, Wp, Wf, WpA, WfsA, counts, G);
    hipLaunchKernelGGL(k_hist_rank, dim3(1024), dim3(256), 0, stream, fid, counts, rank, N);
    hipLaunchKernelGGL(k_scan,      dim3(1), dim3(256), 0, stream, counts, offsets, G);
    hipLaunchKernelGGL(k_scatter,   dim3(1024), dim3(256), 0, stream, fid, rank, offsets, idx, N);
    hipLaunchKernelGGL(k_reduce,    dim3(G / 4), dim3(256), 0, stream,
                       x, idx, offsets, counts, pooledH, G);
    hipLaunchKernelGGL(k_mlp,       dim3(G / ROWS), dim3(256), 0, stream,
                       pooledH, WpA, bp, g1, b1, WfsA, bf, g2, b2, out, G);
}

// Round 9
// 149.743 us; speedup vs baseline: 2.5959x; 1.0074x over previous
//
#include <hip/hip_runtime.h>

#define H    256
#define H2   512
#define ROWS 16
#define LN_EPS 1e-5f

typedef _Float16 half4v __attribute__((ext_vector_type(4)));
typedef float    f32x4  __attribute__((ext_vector_type(4)));

// ---------------- prep: zero counts + build fragment-ordered f16 weights ----------------
// WpA layout: quad q = ((kb16*16 + nb)*64 + lane); element j of quad = Wp[k][n]
// with k = kb16*16 + 4*(lane>>4) + j, n = nb*16 + (lane&15).  (A-fragment order for
// v_mfma_f32_16x16x16_f16 with A = W^T tile; mapping verified by round-3 pass.)

__global__ __launch_bounds__(256) void k_prep(const float* __restrict__ Wp,
        const float* __restrict__ Wf, _Float16* __restrict__ WpA,
        _Float16* __restrict__ WfsA, int* __restrict__ counts, int G) {
    const int tid = blockIdx.x * 256 + threadIdx.x;
    const int stride = gridDim.x * 256;
    for (int i = tid; i < G; i += stride) counts[i] = 0;
    for (int q = tid; q < 32 * 16 * 64; q += stride) {          // GEMM1: K=512 -> 32 kb16
        const int l  = q & 63;
        const int nb = (q >> 6) & 15;
        const int kb = q >> 10;
        const int n  = nb * 16 + (l & 15);
        const int k  = kb * 16 + 4 * (l >> 4);
        half4v v;
        v[0] = (_Float16)Wp[(size_t)(k + 0) * H + n];
        v[1] = (_Float16)Wp[(size_t)(k + 1) * H + n];
        v[2] = (_Float16)Wp[(size_t)(k + 2) * H + n];
        v[3] = (_Float16)Wp[(size_t)(k + 3) * H + n];
        *(half4v*)&WpA[(size_t)q * 4] = v;
    }
    for (int q = tid; q < 16 * 16 * 64; q += stride) {          // GEMM2: K=256, Wf folded 3->1
        const int l  = q & 63;
        const int nb = (q >> 6) & 15;
        const int kb = q >> 10;
        const int n  = nb * 16 + (l & 15);
        const int k  = kb * 16 + 4 * (l >> 4);
        half4v v;
        #pragma unroll
        for (int j = 0; j < 4; ++j) {
            const int kj = k + j;
            v[j] = (_Float16)(Wf[(size_t)kj * H + n] + Wf[(size_t)(kj + H) * H + n]
                              + Wf[(size_t)(kj + 2 * H) * H + n]);
        }
        *(half4v*)&WfsA[(size_t)q * 4] = v;
    }
}

// ---------------- counting sort (non-cooperative 3-kernel chain) ----------------

__global__ void k_hist_rank(const int* __restrict__ fid, int* __restrict__ counts,
                            int* __restrict__ rank, int N) {
    int i = blockIdx.x * blockDim.x + threadIdx.x;
    int stride = gridDim.x * blockDim.x;
    for (; i < N; i += stride) rank[i] = atomicAdd(&counts[fid[i]], 1);
}

// 256-thread shuffle scan over G counters
__global__ __launch_bounds__(256) void k_scan(const int* __restrict__ counts,
                                              int* __restrict__ offsets, int G) {
    __shared__ int wsum[4];
    const int tt = threadIdx.x;
    const int lane = tt & 63, ww = tt >> 6;
    const int base = tt * 32;
    int pre[32];
    int s = 0;
    if (base + 32 <= G) {
        #pragma unroll
        for (int j = 0; j < 32; j += 4) {
            int4 c = *(const int4*)&counts[base + j];
            pre[j]     = s; s += c.x;
            pre[j + 1] = s; s += c.y;
            pre[j + 2] = s; s += c.z;
            pre[j + 3] = s; s += c.w;
        }
    } else {
        #pragma unroll
        for (int j = 0; j < 32; ++j) {
            int c = (base + j < G) ? counts[base + j] : 0;
            pre[j] = s; s += c;
        }
    }
    int inc = s;
    #pragma unroll
    for (int off = 1; off < 64; off <<= 1) {
        int u = __shfl_up(inc, off, 64);
        if (lane >= off) inc += u;
    }
    if (lane == 63) wsum[ww] = inc;
    __syncthreads();
    int wb = 0;
    #pragma unroll
    for (int i = 0; i < 4; ++i) wb += (i < ww) ? wsum[i] : 0;
    const int tb = wb + inc - s;                // exclusive base for this thread
    if (base + 32 <= G) {
        #pragma unroll
        for (int j = 0; j < 32; j += 4) {
            int4 o = make_int4(tb + pre[j], tb + pre[j + 1], tb + pre[j + 2], tb + pre[j + 3]);
            *(int4*)&offsets[base + j] = o;
        }
    } else {
        for (int j = 0; j < 32; ++j)
            if (base + j < G) offsets[base + j] = tb + pre[j];
    }
}

// fid/rank are dead after this kernel -> non-temporal reads keep L2 for reused data
__global__ void k_scatter(const int* __restrict__ fid, const int* __restrict__ rank,
                          const int* __restrict__ offsets,
                          int* __restrict__ idx_sorted, int N) {
    int i = blockIdx.x * blockDim.x + threadIdx.x;
    int stride = gridDim.x * blockDim.x;
    for (; i < N; i += stride) {
        int f = __builtin_nontemporal_load(&fid[i]);
        int r = __builtin_nontemporal_load(&rank[i]);
        idx_sorted[offsets[f] + r] = i;
    }
}

// ---------------- segment mean+max gather ----------------
// 1 wave/group. Per 64-row chunk: ONE coalesced idx load, __shfl broadcasts.
// Next chunk's idx load issued BEFORE consuming current chunk (hides 4B load latency).
// x rows are use-once random 1KB reads -> NON-TEMPORAL (bypass L2/L3 allocation).

__global__ __launch_bounds__(256, 4) void k_reduce(const float* __restrict__ x,
        const int* __restrict__ idx, const int* __restrict__ offsets,
        const int* __restrict__ counts, _Float16* __restrict__ pooledH, int G) {
    const int g = blockIdx.x * 4 + (threadIdx.x >> 6);
    if (g >= G) return;
    const int t = threadIdx.x & 63;
    const int start = offsets[g];
    const int cnt   = counts[g];
    const f32x4* __restrict__ xv = (const f32x4*)x;

    f32x4 s = (f32x4)(0.f);
    f32x4 m = (f32x4)(-__builtin_inff());

    // preload chunk 0 indices
    int lidx = (cnt > 0) ? idx[start + ((t < cnt) ? t : (cnt - 1))] : 0;

    for (int base = 0; base < cnt; base += 64) {
        const int rem = min(cnt - base, 64);
        const int cur = lidx;
        // issue next chunk's idx load early (hides under this chunk's gathers)
        const int nbase = base + 64;
        if (nbase < cnt) {
            const int nrem = cnt - nbase;
            lidx = idx[start + nbase + ((t < nrem) ? t : (nrem - 1))];
        }
        int j = 0;
        for (; j + 8 <= rem; j += 8) {
            f32x4 r0 = __builtin_nontemporal_load(&xv[(size_t)__shfl(cur, j + 0, 64) * 64 + t]);
            f32x4 r1 = __builtin_nontemporal_load(&xv[(size_t)__shfl(cur, j + 1, 64) * 64 + t]);
            f32x4 r2 = __builtin_nontemporal_load(&xv[(size_t)__shfl(cur, j + 2, 64) * 64 + t]);
            f32x4 r3 = __builtin_nontemporal_load(&xv[(size_t)__shfl(cur, j + 3, 64) * 64 + t]);
            f32x4 r4 = __builtin_nontemporal_load(&xv[(size_t)__shfl(cur, j + 4, 64) * 64 + t]);
            f32x4 r5 = __builtin_nontemporal_load(&xv[(size_t)__shfl(cur, j + 5, 64) * 64 + t]);
            f32x4 r6 = __builtin_nontemporal_load(&xv[(size_t)__shfl(cur, j + 6, 64) * 64 + t]);
            f32x4 r7 = __builtin_nontemporal_load(&xv[(size_t)__shfl(cur, j + 7, 64) * 64 + t]);
            s += ((r0 + r1) + (r2 + r3)) + ((r4 + r5) + (r6 + r7));
            #pragma unroll
            for (int e = 0; e < 4; ++e) {
                float mm = fmaxf(fmaxf(fmaxf(r0[e], r1[e]), fmaxf(r2[e], r3[e])),
                                 fmaxf(fmaxf(r4[e], r5[e]), fmaxf(r6[e], r7[e])));
                m[e] = fmaxf(m[e], mm);
            }
        }
        for (; j < rem; ++j) {
            f32x4 a = __builtin_nontemporal_load(&xv[(size_t)__shfl(cur, j, 64) * 64 + t]);
            s += a;
            #pragma unroll
            for (int e = 0; e < 4; ++e) m[e] = fmaxf(m[e], a[e]);
        }
    }
    const float inv = 1.0f / (float)((cnt > 1) ? cnt : 1);
    half4v mh, xh;
    mh[0] = (_Float16)(s[0] * inv); mh[1] = (_Float16)(s[1] * inv);
    mh[2] = (_Float16)(s[2] * inv); mh[3] = (_Float16)(s[3] * inv);
    xh[0] = (_Float16)m[0]; xh[1] = (_Float16)m[1];
    xh[2] = (_Float16)m[2]; xh[3] = (_Float16)m[3];
    *(half4v*)&pooledH[(size_t)g * H2 + 4 * t]     = mh;   // mean -> cols [0,256)
    *(half4v*)&pooledH[(size_t)g * H2 + H + 4 * t] = xh;   // max  -> cols [256,512)
}

// ---------------- fused MLP, MFMA f16, fragment-ordered LDS (all b64 linear) ----------------
// D^T = W^T(A) x pooled^T(B). Lane l, reg r of fragment (nb): row m = l&15,
// col n = nb*16 + 4*(l>>4) + r. LN1 output writes land exactly on GEMM2 B slots.

__global__ __launch_bounds__(256) void k_mlp(const _Float16* __restrict__ pooledH,
        const _Float16* __restrict__ WpA, const float* __restrict__ bp,
        const float* __restrict__ g1, const float* __restrict__ b1,
        const _Float16* __restrict__ WfsA, const float* __restrict__ bf,
        const float* __restrict__ g2, const float* __restrict__ b2,
        float* __restrict__ out, int G) {
    __shared__ _Float16 spB[32 * 64 * 4];   // 16 KB: pooled B-fragments (32 kb16)
    __shared__ _Float16 sA[4 * 16 * 64 * 4];// 32 KB: weight A-fragment tile (4 kb16 x 16 nb)
    __shared__ _Float16 sfB[16 * 64 * 4];   //  8 KB: func B-fragments (16 kb16)
    __shared__ float red[4][16][2];

    const int t   = threadIdx.x;
    const int l   = t & 63;
    const int w   = t >> 6;
    const int li  = l & 15;
    const int grp = l >> 4;
    const int g0  = blockIdx.x * ROWS;

    // stage pooled rows into fragment-ordered spB (b64 linear LDS writes)
    #pragma unroll
    for (int jj = 0; jj < 8; ++jj) {
        const int q = t + jj * 256;
        const int kb16 = q >> 6, ll = q & 63;
        *(half4v*)&spB[q * 4] =
            *(const half4v*)&pooledH[(size_t)(g0 + (ll & 15)) * H2 + kb16 * 16 + 4 * (ll >> 4)];
    }

    f32x4 acc[4];
    #pragma unroll
    for (int f = 0; f < 4; ++f) acc[f] = (f32x4)(0.f);

    // ---- GEMM1: K = 512, tiles of 64
    for (int k0 = 0; k0 < H2; k0 += 64) {
        {
            const int4* src = (const int4*)WpA + (size_t)(k0 >> 4) * 512;
            int4* dst = (int4*)sA;
            #pragma unroll
            for (int jj = 0; jj < 8; ++jj) dst[t + jj * 256] = src[t + jj * 256];
        }
        __syncthreads();
        #pragma unroll
        for (int kb = 0; kb < 4; ++kb) {
            half4v bfrag = *(const half4v*)&spB[(((k0 >> 4) + kb) * 64 + l) * 4];
            #pragma unroll
            for (int f = 0; f < 4; ++f) {
                const int nb = 4 * w + f;
                half4v afrag = *(const half4v*)&sA[((kb * 16 + nb) * 64 + l) * 4];
                acc[f] = __builtin_amdgcn_mfma_f32_16x16x16f16(afrag, bfrag, acc[f], 0, 0, 0);
            }
        }
        __syncthreads();
    }

    // ---- bias + LN1 + ReLU -> sfB (writes are this lane's own GEMM2 B slots)
    {
        f32x4 vv[4], g1v[4], b1v[4];
        float sum = 0.f, sq = 0.f;
        #pragma unroll
        for (int f = 0; f < 4; ++f) {
            const int n0 = 64 * w + 16 * f + 4 * grp;
            f32x4 bb = *(const f32x4*)&bp[n0];
            g1v[f] = *(const f32x4*)&g1[n0];
            b1v[f] = *(const f32x4*)&b1[n0];
            #pragma unroll
            for (int r = 0; r < 4; ++r) {
                float v = acc[f][r] + bb[r];
                vv[f][r] = v;
                sum += v; sq += v * v;
            }
        }
        sum += __shfl_xor(sum, 16, 64); sq += __shfl_xor(sq, 16, 64);
        sum += __shfl_xor(sum, 32, 64); sq += __shfl_xor(sq, 32, 64);
        if (grp == 0) { red[w][li][0] = sum; red[w][li][1] = sq; }
        __syncthreads();
        const float S = red[0][li][0] + red[1][li][0] + red[2][li][0] + red[3][li][0];
        const float Q = red[0][li][1] + red[1][li][1] + red[2][li][1] + red[3][li][1];
        const float mu  = S * (1.0f / H);
        const float var = Q * (1.0f / H) - mu * mu;
        const float rs  = rsqrtf(var + LN_EPS);
        #pragma unroll
        for (int f = 0; f < 4; ++f) {
            half4v hv;
            #pragma unroll
            for (int r = 0; r < 4; ++r)
                hv[r] = (_Float16)fmaxf((vv[f][r] - mu) * rs * g1v[f][r] + b1v[f][r], 0.f);
            *(half4v*)&sfB[((4 * w + f) * 64 + l) * 4] = hv;
        }
    }

    // ---- GEMM2: K = 256, tiles of 64
    f32x4 acc2[4];
    #pragma unroll
    for (int f = 0; f < 4; ++f) acc2[f] = (f32x4)(0.f);

    for (int k0 = 0; k0 < H; k0 += 64) {
        {
            const int4* src = (const int4*)WfsA + (size_t)(k0 >> 4) * 512;
            int4* dst = (int4*)sA;
            #pragma unroll
            for (int jj = 0; jj < 8; ++jj) dst[t + jj * 256] = src[t + jj * 256];
        }
        __syncthreads();
        #pragma unroll
        for (int kb = 0; kb < 4; ++kb) {
            half4v bfrag = *(const half4v*)&sfB[(((k0 >> 4) + kb) * 64 + l) * 4];
            #pragma unroll
            for (int f = 0; f < 4; ++f) {
                const int nb = 4 * w + f;
                half4v afrag = *(const half4v*)&sA[((kb * 16 + nb) * 64 + l) * 4];
                acc2[f] = __builtin_amdgcn_mfma_f32_16x16x16f16(afrag, bfrag, acc2[f], 0, 0, 0);
            }
        }
        __syncthreads();
    }

    // ---- bias + LN2 + ReLU -> out
    {
        f32x4 vv[4], g2v[4], b2v[4];
        float sum = 0.f, sq = 0.f;
        #pragma unroll
        for (int f = 0; f < 4; ++f) {
            const int n0 = 64 * w + 16 * f + 4 * grp;
            f32x4 bb = *(const f32x4*)&bf[n0];
            g2v[f] = *(const f32x4*)&g2[n0];
            b2v[f] = *(const f32x4*)&b2[n0];
            #pragma unroll
            for (int r = 0; r < 4; ++r) {
                float v = acc2[f][r] + bb[r];
                vv[f][r] = v;
                sum += v; sq += v * v;
            }
        }
        sum += __shfl_xor(sum, 16, 64); sq += __shfl_xor(sq, 16, 64);
        sum += __shfl_xor(sum, 32, 64); sq += __shfl_xor(sq, 32, 64);
        if (grp == 0) { red[w][li][0] = sum; red[w][li][1] = sq; }
        __syncthreads();
        const float S = red[0][li][0] + red[1][li][0] + red[2][li][0] + red[3][li][0];
        const float Q = red[0][li][1] + red[1][li][1] + red[2][li][1] + red[3][li][1];
        const float mu  = S * (1.0f / H);
        const float var = Q * (1.0f / H) - mu * mu;
        const float rs  = rsqrtf(var + LN_EPS);
        const int grow = g0 + li;
        #pragma unroll
        for (int f = 0; f < 4; ++f) {
            const int n0 = 64 * w + 16 * f + 4 * grp;
            f32x4 o;
            #pragma unroll
            for (int r = 0; r < 4; ++r)
                o[r] = fmaxf((vv[f][r] - mu) * rs * g2v[f][r] + b2v[f][r], 0.f);
            if (grow < G) *(f32x4*)&out[(size_t)grow * H + n0] = o;
        }
    }
}

// ---------------- launch ----------------

extern "C" void kernel_launch(void* const* d_in, const int* in_sizes, int n_in,
                              void* d_out, int out_size, void* d_ws, size_t ws_size,
                              hipStream_t stream) {
    const float* x   = (const float*)d_in[0];
    const int*   fid = (const int*)d_in[2];
    const float* Wp  = (const float*)d_in[3];
    const float* bp  = (const float*)d_in[4];
    const float* g1  = (const float*)d_in[5];
    const float* b1  = (const float*)d_in[6];
    const float* Wf  = (const float*)d_in[7];
    const float* bf  = (const float*)d_in[8];
    const float* g2  = (const float*)d_in[9];
    const float* b2  = (const float*)d_in[10];
    float* out = (float*)d_out;

    const int N = in_sizes[1];              // 500000
    const int G = out_size / H;             // 8192

    char* w = (char*)d_ws;
    int* counts  = (int*)w;  w += (size_t)G * sizeof(int);
    int* offsets = (int*)w;  w += (size_t)G * sizeof(int);
    int* rank    = (int*)w;  w += (size_t)N * sizeof(int);
    int* idx     = (int*)w;  w += (size_t)N * sizeof(int);
    w = (char*)(((uintptr_t)w + 15) & ~(uintptr_t)15);
    _Float16* pooledH = (_Float16*)w; w += (size_t)G * H2 * sizeof(_Float16);
    _Float16* WpA     = (_Float16*)w; w += (size_t)H2 * H * sizeof(_Float16);
    _Float16* WfsA    = (_Float16*)w; w += (size_t)H * H * sizeof(_Float16);

    hipLaunchKernelGGL(k_prep,      dim3(128), dim3(256), 0, stream, Wp, Wf, WpA, WfsA, counts, G);
    hipLaunchKernelGGL(k_hist_rank, dim3(1024), dim3(256), 0, stream, fid, counts, rank, N);
    hipLaunchKernelGGL(k_scan,      dim3(1), dim3(256), 0, stream, counts, offsets, G);
    hipLaunchKernelGGL(k_scatter,   dim3(1024), dim3(256), 0, stream, fid, rank, offsets, idx, N);
    hipLaunchKernelGGL(k_reduce,    dim3(G / 4), dim3(256), 0, stream,
                       x, idx, offsets, counts, pooledH, G);
    hipLaunchKernelGGL(k_mlp,       dim3(G / ROWS), dim3(256), 0, stream,
                       pooledH, WpA, bp, g1, b1, WfsA, bf, g2, b2, out, G);
}